// Round 2
// baseline (812.215 us; speedup 1.0000x reference)
//
#include <hip/hip_runtime.h>
#include <math.h>

typedef __bf16 bf16_t;
typedef __attribute__((ext_vector_type(4))) float f32x4;
typedef __attribute__((ext_vector_type(8))) __bf16 v8bf;
typedef __attribute__((ext_vector_type(4))) __bf16 v4bf;

#define GLOAD_LDS16(g, l)                                                     \
  __builtin_amdgcn_global_load_lds(                                           \
      (const __attribute__((address_space(1))) void*)(g),                     \
      (__attribute__((address_space(3))) void*)(l), 16, 0, 0)

// ---------------- diagnostic sentinel ----------------
__global__ void sentinel_kernel(float* o, float v) { o[0] = v; }

// ---------------- pack kernels ----------------
// Xcat[m, 0:1024] = bf16(xa[m,:]); Xcat[m, 1024:2048] = bf16(xb[m,:])
__global__ __launch_bounds__(256) void pack_x_kernel(
    const float* __restrict__ xa, const float* __restrict__ xb,
    bf16_t* __restrict__ xcat, int n4)
{
  int i = blockIdx.x * 256 + threadIdx.x;
  if (i >= n4) return;
  float4 a = reinterpret_cast<const float4*>(xa)[i];
  float4 b = reinterpret_cast<const float4*>(xb)[i];
  long e = (long)i * 4;
  long m = e >> 10;
  int  d = (int)(e & 1023);
  v4bf av = { (bf16_t)a.x, (bf16_t)a.y, (bf16_t)a.z, (bf16_t)a.w };
  v4bf bv = { (bf16_t)b.x, (bf16_t)b.y, (bf16_t)b.z, (bf16_t)b.w };
  *reinterpret_cast<v4bf*>(xcat + m * 2048 + d)        = av;
  *reinterpret_cast<v4bf*>(xcat + m * 2048 + 1024 + d) = bv;
}

// outA[n] = [wa[n,:] | j2*wb[n,:]] ; outB[n] = [wb[n,:] | wa[n,:]]   (1024x1024 inputs)
__global__ __launch_bounds__(256) void pack_w_kernel(
    const float* __restrict__ wa, const float* __restrict__ wb,
    bf16_t* __restrict__ outA, bf16_t* __restrict__ outB, float j2)
{
  int i = blockIdx.x * 256 + threadIdx.x;   // 0..262143, exact
  float4 a = reinterpret_cast<const float4*>(wa)[i];
  float4 b = reinterpret_cast<const float4*>(wb)[i];
  long e = (long)i * 4;
  long n = e >> 10;
  int  k = (int)(e & 1023);
  v4bf av = { (bf16_t)a.x, (bf16_t)a.y, (bf16_t)a.z, (bf16_t)a.w };
  v4bf bv = { (bf16_t)b.x, (bf16_t)b.y, (bf16_t)b.z, (bf16_t)b.w };
  v4bf jb = { (bf16_t)(j2*b.x), (bf16_t)(j2*b.y), (bf16_t)(j2*b.z), (bf16_t)(j2*b.w) };
  *reinterpret_cast<v4bf*>(outA + n * 2048 + k)        = av;
  *reinterpret_cast<v4bf*>(outA + n * 2048 + 1024 + k) = jb;
  *reinterpret_cast<v4bf*>(outB + n * 2048 + k)        = bv;
  *reinterpret_cast<v4bf*>(outB + n * 2048 + 1024 + k) = av;
}

// ---------------- generic bf16 GEMM, C = A @ B^T ----------------
// A: [M,K] row-major bf16 (lda), B: [N,K] row-major bf16 (ldb).
// 128x128 tile, BK=64, 4 waves (2x2), each wave 64x64 = 4x4 frags of 16x16x32.
// mode 0: outf fp32 (+bias). mode 1: o1 bf16 = s1*(acc+bias).
// mode 2: additionally o2 bf16 = s2*(acc+bias).
__global__ __launch_bounds__(256) void gemm_bt_kernel(
    const bf16_t* __restrict__ A, const bf16_t* __restrict__ B,
    int K, long lda, long ldb, long bsA, long bsB,
    int mode, const float* __restrict__ bias,
    float* __restrict__ outf, long ldof, long bsOf,
    bf16_t* __restrict__ o1, float s1,
    bf16_t* __restrict__ o2, float s2,
    long ldo, long bsO)
{
  constexpr int BK = 64;
  __shared__ __align__(16) bf16_t As[128 * BK];
  __shared__ __align__(16) bf16_t Bs[128 * BK];
  const int tid  = threadIdx.x;
  const int wave = tid >> 6;
  const int lane = tid & 63;
  const int rr = lane & 15;      // fragment row (A) / col (C)
  const int kg = lane >> 4;      // k-group / C row group
  const long row0 = (long)blockIdx.y * 128;
  const long col0 = (long)blockIdx.x * 128;
  const int z = blockIdx.z;
  const bf16_t* Ab = A + (long)z * bsA + row0 * lda;
  const bf16_t* Bb = B + (long)z * bsB + col0 * ldb;
  const int wm = (wave >> 1) * 64;
  const int wn = (wave & 1) * 64;

  f32x4 acc[4][4];
#pragma unroll
  for (int i = 0; i < 4; ++i)
#pragma unroll
    for (int j = 0; j < 4; ++j) acc[i][j] = (f32x4){0.f, 0.f, 0.f, 0.f};

  const int r_st  = tid >> 3;        // staging row within 32-row chunk
  const int cb_st = (tid & 7) * 8;   // staging col (elements)

  for (int kt = 0; kt < K; kt += BK) {
#pragma unroll
    for (int it = 0; it < 4; ++it) {
      const int r = it * 32 + r_st;
      const bf16_t* ga = Ab + (long)r * lda + kt + cb_st;
      const bf16_t* gb = Bb + (long)r * ldb + kt + cb_st;
      // wave-uniform LDS base; HW adds lane*16B
      bf16_t* la = As + (size_t)(it * 256 + wave * 64) * 8;
      bf16_t* lb = Bs + (size_t)(it * 256 + wave * 64) * 8;
      GLOAD_LDS16(ga, la);
      GLOAD_LDS16(gb, lb);
    }
    __syncthreads();
#pragma unroll
    for (int ks = 0; ks < 2; ++ks) {
      const int ko = ks * 32 + kg * 8;
      v8bf a[4], b[4];
#pragma unroll
      for (int i = 0; i < 4; ++i)
        a[i] = *reinterpret_cast<const v8bf*>(As + (wm + i * 16 + rr) * BK + ko);
#pragma unroll
      for (int j = 0; j < 4; ++j)
        b[j] = *reinterpret_cast<const v8bf*>(Bs + (wn + j * 16 + rr) * BK + ko);
#pragma unroll
      for (int i = 0; i < 4; ++i)
#pragma unroll
        for (int j = 0; j < 4; ++j)
          acc[i][j] = __builtin_amdgcn_mfma_f32_16x16x32_bf16(a[i], b[j], acc[i][j], 0, 0, 0);
    }
    __syncthreads();
  }

  // epilogue: C/D layout col=lane&15, row=(lane>>4)*4+reg  [m89-verified]
#pragma unroll
  for (int i = 0; i < 4; ++i) {
    const long mrow = row0 + wm + i * 16 + kg * 4;
#pragma unroll
    for (int j = 0; j < 4; ++j) {
      const long col = col0 + wn + j * 16 + rr;
      const float bv = bias ? bias[col] : 0.f;
#pragma unroll
      for (int r2 = 0; r2 < 4; ++r2) {
        const float v = acc[i][j][r2] + bv;
        const long row = mrow + r2;
        if (mode == 0) {
          outf[(long)z * bsOf + row * ldof + col] = v;
        } else {
          o1[(long)z * bsO + row * ldo + col] = (bf16_t)(s1 * v);
          if (mode == 2)
            o2[(long)z * bsO + row * ldo + col] = (bf16_t)(s2 * v);
        }
      }
    }
  }
}

// ---------------- V transpose ----------------
// src [Mc, 2048] (Va|Vb concat), per 64x64 tile -> dst[b][dstoff+c][t] (b = chunk-local batch)
__global__ __launch_bounds__(256) void transpose_v_kernel(
    const bf16_t* __restrict__ src, bf16_t* __restrict__ dst,
    int srcoff, int dstoff)
{
  __shared__ bf16_t t[64][65];
  const int tid = threadIdx.x;
  const long c0 = (long)blockIdx.x * 64;
  const long g0 = (long)blockIdx.y * 64;   // chunk-local token row (2048 % 64 == 0)
#pragma unroll
  for (int it = 0; it < 16; ++it) {
    int idx = it * 256 + tid;
    int r = idx >> 6, c = idx & 63;
    t[r][c] = src[(g0 + r) * 2048 + srcoff + c0 + c];
  }
  __syncthreads();
  const long b  = g0 >> 11;
  const long t0 = g0 & 2047;
#pragma unroll
  for (int it = 0; it < 16; ++it) {
    int idx = it * 256 + tid;
    int nr = idx >> 6, tc = idx & 63;
    dst[b * 4194304 + (dstoff + c0 + nr) * 2048 + t0 + tc] = t[tc][nr];
  }
}

// ---------------- magnitude + softmax: attn = softmax(sqrt(sa^2+sb^2)) ----------------
// (1/sqrt(D) already folded into Q). One block per row of 2048. In-place safe (attn==sa).
__global__ __launch_bounds__(256) void softmax_mag_kernel(
    const bf16_t* __restrict__ sa, const bf16_t* __restrict__ sb,
    bf16_t* __restrict__ attn)
{
  const int tid = threadIdx.x;
  const long base = (long)blockIdx.x * 2048;
  v4bf a0 = *reinterpret_cast<const v4bf*>(sa + base + tid * 4);
  v4bf a1 = *reinterpret_cast<const v4bf*>(sa + base + 1024 + tid * 4);
  v4bf b0 = *reinterpret_cast<const v4bf*>(sb + base + tid * 4);
  v4bf b1 = *reinterpret_cast<const v4bf*>(sb + base + 1024 + tid * 4);
  float r[8];
#pragma unroll
  for (int k = 0; k < 4; ++k) {
    float x = (float)a0[k], y = (float)b0[k];
    r[k] = sqrtf(x * x + y * y);
  }
#pragma unroll
  for (int k = 0; k < 4; ++k) {
    float x = (float)a1[k], y = (float)b1[k];
    r[4 + k] = sqrtf(x * x + y * y);
  }
  float m = r[0];
#pragma unroll
  for (int k = 1; k < 8; ++k) m = fmaxf(m, r[k]);
#pragma unroll
  for (int off = 32; off > 0; off >>= 1) m = fmaxf(m, __shfl_xor(m, off));
  __shared__ float red[8];
  if ((tid & 63) == 0) red[tid >> 6] = m;
  __syncthreads();
  m = fmaxf(fmaxf(red[0], red[1]), fmaxf(red[2], red[3]));
  float p[8], s = 0.f;
#pragma unroll
  for (int k = 0; k < 8; ++k) { p[k] = __expf(r[k] - m); s += p[k]; }
#pragma unroll
  for (int off = 32; off > 0; off >>= 1) s += __shfl_xor(s, off);
  if ((tid & 63) == 0) red[4 + (tid >> 6)] = s;
  __syncthreads();
  const float inv = 1.f / (red[4] + red[5] + red[6] + red[7]);
  v4bf o0 = { (bf16_t)(p[0]*inv), (bf16_t)(p[1]*inv), (bf16_t)(p[2]*inv), (bf16_t)(p[3]*inv) };
  v4bf o1 = { (bf16_t)(p[4]*inv), (bf16_t)(p[5]*inv), (bf16_t)(p[6]*inv), (bf16_t)(p[7]*inv) };
  *reinterpret_cast<v4bf*>(attn + base + tid * 4)        = o0;
  *reinterpret_cast<v4bf*>(attn + base + 1024 + tid * 4) = o1;
}

// ---------------- host ----------------
extern "C" void kernel_launch(void* const* d_in, const int* in_sizes, int n_in,
                              void* d_out, int out_size, void* d_ws, size_t ws_size,
                              hipStream_t stream)
{
  (void)in_sizes; (void)n_in; (void)out_size;
  const float* xa = (const float*)d_in[0];
  const float* xb = (const float*)d_in[1];
  const float *w_a[4], *w_b[4], *b_a[4], *b_b[4];
  for (int p = 0; p < 4; ++p) {
    w_a[p] = (const float*)d_in[2 + p*4 + 0];
    w_b[p] = (const float*)d_in[2 + p*4 + 1];
    b_a[p] = (const float*)d_in[2 + p*4 + 2];
    b_b[p] = (const float*)d_in[2 + p*4 + 3];
  }
  float* out = (float*)d_out;
  const float neg_c2 = (float)(-cos(2.0));  // j2 = -cos(2*theta)|theta=1 == -cos(2)

  // ---- adaptive workspace tiers ----
  // regions (bf16 [Mc,2048], Mc = NB*2048): R0 Xcat/sa/attn, R1 Qcat/outc,
  // R2 K1=[Ka|-c2 Kb], R3 K2=[Kb|Ka], R4 VaVb/sb, R5 Vt. Plus packed weights.
  const size_t WFULL = 33554432ull;  // 8 x [1024,2048] bf16
  const size_t WSLOT = 8388608ull;   // 2 x [1024,2048] bf16 (re-packed per use)
  int NB = 0; bool fullW = true;
  if      (ws_size >= WFULL + 6ull * 4ull * 8388608ull) NB = 4;               // 224 MiB
  else if (ws_size >= WFULL + 6ull * 2ull * 8388608ull) NB = 2;               // 128 MiB
  else if (ws_size >= WFULL + 6ull * 1ull * 8388608ull) NB = 1;               //  80 MiB
  else if (ws_size >= WSLOT + 6ull * 1ull * 8388608ull) { NB = 1; fullW = false; } // 56 MiB
  else {
    // diagnostic: absmax error will report ~ws_size so we learn the real budget
    sentinel_kernel<<<1, 1, 0, stream>>>(out, (float)ws_size);
    return;
  }

  char* ws = (char*)d_ws;
  const size_t wbytes = fullW ? WFULL : WSLOT;
  const size_t RB = (size_t)NB * 8388608ull;
  bf16_t* W  = (bf16_t*)ws;
  bf16_t* R0 = (bf16_t*)(ws + wbytes);
  bf16_t* R1 = (bf16_t*)(ws + wbytes + 1*RB);
  bf16_t* R2 = (bf16_t*)(ws + wbytes + 2*RB);
  bf16_t* R3 = (bf16_t*)(ws + wbytes + 3*RB);
  bf16_t* R4 = (bf16_t*)(ws + wbytes + 4*RB);
  bf16_t* R5 = (bf16_t*)(ws + wbytes + 5*RB);

  const int  Mc = NB * 2048;
  const dim3 blk(256);
  const dim3 gproj(8, Mc / 128, 1);
  const dim3 gsq(16, 16, NB);
  const dim3 gtr(16, Mc / 64, 1);

  auto WA = [&](int p) -> bf16_t* { return fullW ? W + (size_t)p * 4194304ull : W; };
  auto WB = [&](int p) -> bf16_t* { return WA(p) + 2097152ull; };

  if (fullW)
    for (int p = 0; p < 4; ++p)
      pack_w_kernel<<<1024, blk, 0, stream>>>(w_a[p], w_b[p], WA(p), WB(p), neg_c2);

  for (int c = 0; c < 4 / NB; ++c) {
    const size_t xoff = (size_t)c * NB * 2097152ull;  // floats per chunk (NB*2048*1024)
    pack_x_kernel<<<Mc, blk, 0, stream>>>(xa + xoff, xb + xoff, R0, Mc * 256);

    // Q projection (1/sqrt(D)=1/32 folded into Q, exact in bf16)
    if (!fullW) pack_w_kernel<<<1024, blk, 0, stream>>>(w_a[0], w_b[0], WA(0), WB(0), neg_c2);
    gemm_bt_kernel<<<gproj, blk, 0, stream>>>(R0, WA(0), 2048, 2048, 2048, 0, 0,
        1, b_a[0], nullptr, 0, 0, R1,        0.03125f, nullptr, 0.f, 2048, 0);
    gemm_bt_kernel<<<gproj, blk, 0, stream>>>(R0, WB(0), 2048, 2048, 2048, 0, 0,
        1, b_b[0], nullptr, 0, 0, R1 + 1024, 0.03125f, nullptr, 0.f, 2048, 0);

    // K projection, dual writes into concat score-key buffers
    if (!fullW) pack_w_kernel<<<1024, blk, 0, stream>>>(w_a[1], w_b[1], WA(1), WB(1), neg_c2);
    gemm_bt_kernel<<<gproj, blk, 0, stream>>>(R0, WA(1), 2048, 2048, 2048, 0, 0,
        2, b_a[1], nullptr, 0, 0, R2, 1.f, R3 + 1024, 1.f,     2048, 0);
    gemm_bt_kernel<<<gproj, blk, 0, stream>>>(R0, WB(1), 2048, 2048, 2048, 0, 0,
        2, b_b[1], nullptr, 0, 0, R3, 1.f, R2 + 1024, neg_c2,  2048, 0);

    // V projection -> R4 = [Va | Vb]
    if (!fullW) pack_w_kernel<<<1024, blk, 0, stream>>>(w_a[2], w_b[2], WA(2), WB(2), neg_c2);
    gemm_bt_kernel<<<gproj, blk, 0, stream>>>(R0, WA(2), 2048, 2048, 2048, 0, 0,
        1, b_a[2], nullptr, 0, 0, R4,        1.f, nullptr, 0.f, 2048, 0);
    gemm_bt_kernel<<<gproj, blk, 0, stream>>>(R0, WB(2), 2048, 2048, 2048, 0, 0,
        1, b_b[2], nullptr, 0, 0, R4 + 1024, 1.f, nullptr, 0.f, 2048, 0);

    // V transpose into R5 = per-batch [Va^T ; Vb^T]
    transpose_v_kernel<<<gtr, blk, 0, stream>>>(R4, R5, 0,    0);
    transpose_v_kernel<<<gtr, blk, 0, stream>>>(R4, R5, 1024, 1024);

    // scores (bf16): sa = Qcat@K1^T -> R0 (Xcat dead), sb = Qcat@K2^T -> R4 (VaVb dead)
    gemm_bt_kernel<<<gsq, blk, 0, stream>>>(R1, R2, 2048, 2048, 2048, 4194304, 4194304,
        1, nullptr, nullptr, 0, 0, R0, 1.f, nullptr, 0.f, 2048, 4194304);
    gemm_bt_kernel<<<gsq, blk, 0, stream>>>(R1, R3, 2048, 2048, 2048, 4194304, 4194304,
        1, nullptr, nullptr, 0, 0, R4, 1.f, nullptr, 0.f, 2048, 4194304);

    // magnitude + softmax -> bf16 attn (in-place over R0)
    softmax_mag_kernel<<<Mc, blk, 0, stream>>>(R0, R4, R0);

    // [out_a|out_b] = attn @ Vt^T -> R1 (Qcat dead)
    gemm_bt_kernel<<<gsq, blk, 0, stream>>>(R0, R5, 2048, 2048, 2048, 4194304, 4194304,
        1, nullptr, nullptr, 0, 0, R1, 1.f, nullptr, 0.f, 2048, 4194304);

    // O projection -> fp32 outputs
    if (!fullW) pack_w_kernel<<<1024, blk, 0, stream>>>(w_a[3], w_b[3], WA(3), WB(3), neg_c2);
    gemm_bt_kernel<<<gproj, blk, 0, stream>>>(R1, WA(3), 2048, 2048, 2048, 0, 0,
        0, b_a[3], out + xoff,              1024, 0, nullptr, 0.f, nullptr, 0.f, 0, 0);
    gemm_bt_kernel<<<gproj, blk, 0, stream>>>(R1, WB(3), 2048, 2048, 2048, 0, 0,
        0, b_b[3], out + 8388608ull + xoff, 1024, 0, nullptr, 0.f, nullptr, 0.f, 0, 0);
  }
}

// Round 3
// 774.069 us; speedup vs baseline: 1.0493x; 1.0493x over previous
//
#include <hip/hip_runtime.h>
#include <math.h>

typedef __bf16 bf16_t;
typedef __attribute__((ext_vector_type(4))) float f32x4;
typedef __attribute__((ext_vector_type(8))) __bf16 v8bf;
typedef __attribute__((ext_vector_type(4))) __bf16 v4bf;

#define GLOAD_LDS16(g, l)                                                     \
  __builtin_amdgcn_global_load_lds(                                           \
      (const __attribute__((address_space(1))) void*)(g),                     \
      (__attribute__((address_space(3))) void*)(l), 16, 0, 0)

// ---------------- diagnostic sentinel ----------------
__global__ void sentinel_kernel(float* o, float v) { o[0] = v; }

// ---------------- pack kernels ----------------
__global__ __launch_bounds__(256) void pack_x_kernel(
    const float* __restrict__ xa, const float* __restrict__ xb,
    bf16_t* __restrict__ xcat, int n4)
{
  int i = blockIdx.x * 256 + threadIdx.x;
  if (i >= n4) return;
  float4 a = reinterpret_cast<const float4*>(xa)[i];
  float4 b = reinterpret_cast<const float4*>(xb)[i];
  long e = (long)i * 4;
  long m = e >> 10;
  int  d = (int)(e & 1023);
  v4bf av = { (bf16_t)a.x, (bf16_t)a.y, (bf16_t)a.z, (bf16_t)a.w };
  v4bf bv = { (bf16_t)b.x, (bf16_t)b.y, (bf16_t)b.z, (bf16_t)b.w };
  *reinterpret_cast<v4bf*>(xcat + m * 2048 + d)        = av;
  *reinterpret_cast<v4bf*>(xcat + m * 2048 + 1024 + d) = bv;
}

// outA[n] = [wa[n,:] | j2*wb[n,:]] ; outB[n] = [wb[n,:] | wa[n,:]]
__global__ __launch_bounds__(256) void pack_w_kernel(
    const float* __restrict__ wa, const float* __restrict__ wb,
    bf16_t* __restrict__ outA, bf16_t* __restrict__ outB, float j2)
{
  int i = blockIdx.x * 256 + threadIdx.x;   // 0..262143, exact
  float4 a = reinterpret_cast<const float4*>(wa)[i];
  float4 b = reinterpret_cast<const float4*>(wb)[i];
  long e = (long)i * 4;
  long n = e >> 10;
  int  k = (int)(e & 1023);
  v4bf av = { (bf16_t)a.x, (bf16_t)a.y, (bf16_t)a.z, (bf16_t)a.w };
  v4bf bv = { (bf16_t)b.x, (bf16_t)b.y, (bf16_t)b.z, (bf16_t)b.w };
  v4bf jb = { (bf16_t)(j2*b.x), (bf16_t)(j2*b.y), (bf16_t)(j2*b.z), (bf16_t)(j2*b.w) };
  *reinterpret_cast<v4bf*>(outA + n * 2048 + k)        = av;
  *reinterpret_cast<v4bf*>(outA + n * 2048 + 1024 + k) = jb;
  *reinterpret_cast<v4bf*>(outB + n * 2048 + k)        = bv;
  *reinterpret_cast<v4bf*>(outB + n * 2048 + 1024 + k) = av;
}

// ---------------- generic bf16 GEMM, C = A @ B^T, templated epilogue ----------------
// EPI 0: QKV-routed (seg=col>>10): Q->o0(bf16,x1/32), K dual->o1 (Kc), V->o2.
// EPI 1: scores (seg=col>>11): ->o0 (sa) / o1 (sb), bf16, per-batch z.
// EPI 2: PV: o0 bf16 [z][row][col].
// EPI 3: O-proj (seg=col>>10): fp32 -> o0 (out_a) / o1 (out_b), +bias.
template<int EPI>
__global__ __launch_bounds__(256) void gemm_bt_kernel(
    const bf16_t* __restrict__ A, const bf16_t* __restrict__ B,
    int K, long lda, long ldb, long bsA, long bsB,
    void* __restrict__ o0p, void* __restrict__ o1p, void* __restrict__ o2p,
    const float* __restrict__ bb0, const float* __restrict__ bb1,
    const float* __restrict__ bb2, const float* __restrict__ bb3,
    const float* __restrict__ bb4, const float* __restrict__ bb5,
    float scl)
{
  constexpr int BK = 64;
  __shared__ __align__(16) bf16_t As[128 * BK];
  __shared__ __align__(16) bf16_t Bs[128 * BK];
  const int tid  = threadIdx.x;
  const int wave = tid >> 6;
  const int lane = tid & 63;
  const int rr = lane & 15;
  const int kg = lane >> 4;
  const long row0 = (long)blockIdx.y * 128;
  const long col0 = (long)blockIdx.x * 128;
  const int z = blockIdx.z;
  const bf16_t* Ab = A + (long)z * bsA + row0 * lda;
  const bf16_t* Bb = B + (long)z * bsB + col0 * ldb;
  const int wm = (wave >> 1) * 64;
  const int wn = (wave & 1) * 64;

  f32x4 acc[4][4];
#pragma unroll
  for (int i = 0; i < 4; ++i)
#pragma unroll
    for (int j = 0; j < 4; ++j) acc[i][j] = (f32x4){0.f, 0.f, 0.f, 0.f};

  const int r_st  = tid >> 3;
  const int cb_st = (tid & 7) * 8;

  for (int kt = 0; kt < K; kt += BK) {
#pragma unroll
    for (int it = 0; it < 4; ++it) {
      const int r = it * 32 + r_st;
      const bf16_t* ga = Ab + (long)r * lda + kt + cb_st;
      const bf16_t* gb = Bb + (long)r * ldb + kt + cb_st;
      bf16_t* la = As + (size_t)(it * 256 + wave * 64) * 8;
      bf16_t* lb = Bs + (size_t)(it * 256 + wave * 64) * 8;
      GLOAD_LDS16(ga, la);
      GLOAD_LDS16(gb, lb);
    }
    __syncthreads();
#pragma unroll
    for (int ks = 0; ks < 2; ++ks) {
      const int ko = ks * 32 + kg * 8;
      v8bf a[4], b[4];
#pragma unroll
      for (int i = 0; i < 4; ++i)
        a[i] = *reinterpret_cast<const v8bf*>(As + (wm + i * 16 + rr) * BK + ko);
#pragma unroll
      for (int j = 0; j < 4; ++j)
        b[j] = *reinterpret_cast<const v8bf*>(Bs + (wn + j * 16 + rr) * BK + ko);
#pragma unroll
      for (int i = 0; i < 4; ++i)
#pragma unroll
        for (int j = 0; j < 4; ++j)
          acc[i][j] = __builtin_amdgcn_mfma_f32_16x16x32_bf16(a[i], b[j], acc[i][j], 0, 0, 0);
    }
    __syncthreads();
  }

  // C/D layout: col=lane&15, row=(lane>>4)*4+reg  [m89-verified]
#pragma unroll
  for (int i = 0; i < 4; ++i) {
    const long mrow = row0 + wm + i * 16 + kg * 4;
#pragma unroll
    for (int j = 0; j < 4; ++j) {
      const long col = col0 + wn + j * 16 + rr;
#pragma unroll
      for (int r2 = 0; r2 < 4; ++r2) {
        const float v = acc[i][j][r2];
        const long row = mrow + r2;
        if constexpr (EPI == 0) {
          // QKV routing. seg uniform per block (128 | 1024).
          const int  seg = (int)(col >> 10);
          const long c   = col & 1023;
          bf16_t* Q  = (bf16_t*)o0p;
          bf16_t* Kc = (bf16_t*)o1p;
          bf16_t* Vc = (bf16_t*)o2p;
          const long kbase = (row >> 11) * 8388608 + (row & 2047) * 2048;
          switch (seg) {
            case 0: Q[row * 2048 + c]        = (bf16_t)((v + bb0[c]) * 0.03125f); break;
            case 1: Q[row * 2048 + 1024 + c] = (bf16_t)((v + bb1[c]) * 0.03125f); break;
            case 2: { const float w = v + bb2[c];
                      Kc[kbase + c]                   = (bf16_t)w;          // K1 = [Ka | .]
                      Kc[kbase + 4194304 + 1024 + c]  = (bf16_t)w;          // K2 = [. | Ka]
                    } break;
            case 3: { const float w = v + bb3[c];
                      Kc[kbase + 4194304 + c]         = (bf16_t)w;          // K2 = [Kb | .]
                      Kc[kbase + 1024 + c]            = (bf16_t)(scl * w);  // K1 = [. | -c2*Kb]
                    } break;
            case 4: Vc[row * 2048 + c]        = (bf16_t)(v + bb4[c]); break;
            default: Vc[row * 2048 + 1024 + c] = (bf16_t)(v + bb5[c]); break;
          }
        } else if constexpr (EPI == 1) {
          const int  seg = (int)(col >> 11);
          const long c   = col & 2047;
          bf16_t* dst = seg ? (bf16_t*)o1p : (bf16_t*)o0p;
          dst[(long)z * 4194304 + row * 2048 + c] = (bf16_t)v;
        } else if constexpr (EPI == 2) {
          ((bf16_t*)o0p)[(long)z * 4194304 + row * 2048 + col] = (bf16_t)v;
        } else {
          const int  seg = (int)(col >> 10);
          const long c   = col & 1023;
          float* dst = seg ? (float*)o1p : (float*)o0p;
          const float bv = seg ? bb1[c] : bb0[c];
          dst[row * 1024 + c] = v + bv;
        }
      }
    }
  }
}

// ---------------- V transpose ----------------
__global__ __launch_bounds__(256) void transpose_v_kernel(
    const bf16_t* __restrict__ src, bf16_t* __restrict__ dst,
    int srcoff, int dstoff)
{
  __shared__ bf16_t t[64][65];
  const int tid = threadIdx.x;
  const long c0 = (long)blockIdx.x * 64;
  const long g0 = (long)blockIdx.y * 64;
#pragma unroll
  for (int it = 0; it < 16; ++it) {
    int idx = it * 256 + tid;
    int r = idx >> 6, c = idx & 63;
    t[r][c] = src[(g0 + r) * 2048 + srcoff + c0 + c];
  }
  __syncthreads();
  const long b  = g0 >> 11;
  const long t0 = g0 & 2047;
#pragma unroll
  for (int it = 0; it < 16; ++it) {
    int idx = it * 256 + tid;
    int nr = idx >> 6, tc = idx & 63;
    dst[b * 4194304 + (dstoff + c0 + nr) * 2048 + t0 + tc] = t[tc][nr];
  }
}

// ---------------- magnitude + softmax ----------------
__global__ __launch_bounds__(256) void softmax_mag_kernel(
    const bf16_t* __restrict__ sa, const bf16_t* __restrict__ sb,
    bf16_t* __restrict__ attn)
{
  const int tid = threadIdx.x;
  const long base = (long)blockIdx.x * 2048;
  v4bf a0 = *reinterpret_cast<const v4bf*>(sa + base + tid * 4);
  v4bf a1 = *reinterpret_cast<const v4bf*>(sa + base + 1024 + tid * 4);
  v4bf b0 = *reinterpret_cast<const v4bf*>(sb + base + tid * 4);
  v4bf b1 = *reinterpret_cast<const v4bf*>(sb + base + 1024 + tid * 4);
  float r[8];
#pragma unroll
  for (int k = 0; k < 4; ++k) {
    float x = (float)a0[k], y = (float)b0[k];
    r[k] = sqrtf(x * x + y * y);
  }
#pragma unroll
  for (int k = 0; k < 4; ++k) {
    float x = (float)a1[k], y = (float)b1[k];
    r[4 + k] = sqrtf(x * x + y * y);
  }
  float m = r[0];
#pragma unroll
  for (int k = 1; k < 8; ++k) m = fmaxf(m, r[k]);
#pragma unroll
  for (int off = 32; off > 0; off >>= 1) m = fmaxf(m, __shfl_xor(m, off));
  __shared__ float red[8];
  if ((tid & 63) == 0) red[tid >> 6] = m;
  __syncthreads();
  m = fmaxf(fmaxf(red[0], red[1]), fmaxf(red[2], red[3]));
  float p[8], s = 0.f;
#pragma unroll
  for (int k = 0; k < 8; ++k) { p[k] = __expf(r[k] - m); s += p[k]; }
#pragma unroll
  for (int off = 32; off > 0; off >>= 1) s += __shfl_xor(s, off);
  if ((tid & 63) == 0) red[4 + (tid >> 6)] = s;
  __syncthreads();
  const float inv = 1.f / (red[4] + red[5] + red[6] + red[7]);
  v4bf o0 = { (bf16_t)(p[0]*inv), (bf16_t)(p[1]*inv), (bf16_t)(p[2]*inv), (bf16_t)(p[3]*inv) };
  v4bf o1 = { (bf16_t)(p[4]*inv), (bf16_t)(p[5]*inv), (bf16_t)(p[6]*inv), (bf16_t)(p[7]*inv) };
  *reinterpret_cast<v4bf*>(attn + base + tid * 4)        = o0;
  *reinterpret_cast<v4bf*>(attn + base + 1024 + tid * 4) = o1;
}

// ---------------- host ----------------
extern "C" void kernel_launch(void* const* d_in, const int* in_sizes, int n_in,
                              void* d_out, int out_size, void* d_ws, size_t ws_size,
                              hipStream_t stream)
{
  (void)in_sizes; (void)n_in; (void)out_size;
  const float* xa = (const float*)d_in[0];
  const float* xb = (const float*)d_in[1];
  const float *w_a[4], *w_b[4], *b_a[4], *b_b[4];
  for (int p = 0; p < 4; ++p) {
    w_a[p] = (const float*)d_in[2 + p*4 + 0];
    w_b[p] = (const float*)d_in[2 + p*4 + 1];
    b_a[p] = (const float*)d_in[2 + p*4 + 2];
    b_b[p] = (const float*)d_in[2 + p*4 + 3];
  }
  float* out = (float*)d_out;
  const float neg_c2 = (float)(-cos(2.0));

  // ---- adaptive workspace tiers (thresholds identical to the passing round) ----
  const size_t WFULL = 33554432ull;   // 8 weight slots of [1024,2048] bf16
  const size_t WQKV  = 25165824ull;   // 6 slots (low tier: O re-packed over QKV)
  int NB = 0; bool fullW = true;
  if      (ws_size >= WFULL + 6ull * 4ull * 8388608ull) NB = 4;               // 224 MiB
  else if (ws_size >= WFULL + 6ull * 2ull * 8388608ull) NB = 2;               // 128 MiB
  else if (ws_size >= WFULL + 6ull * 1ull * 8388608ull) NB = 1;               //  80 MiB
  else if (ws_size >= WQKV  + 6ull * 1ull * 8388608ull) { NB = 1; fullW = false; } // 72 MiB
  else { sentinel_kernel<<<1, 1, 0, stream>>>(out, (float)ws_size); return; }

  char* ws = (char*)d_ws;
  const size_t wbytes = fullW ? WFULL : WQKV;
  const size_t RB = (size_t)NB * 8388608ull;
  bf16_t* Wqkv = (bf16_t*)ws;                            // 6 x [1024,2048]
  bf16_t* Wo   = fullW ? (bf16_t*)(ws + WQKV) : Wqkv;    // 2 x [1024,2048]
  bf16_t* R0 = (bf16_t*)(ws + wbytes);           // Xcat / sa / attn
  bf16_t* R1 = (bf16_t*)(ws + wbytes + 1*RB);    // Qcat / outc
  bf16_t* Kc = (bf16_t*)(ws + wbytes + 2*RB);    // [NB][2][2048][2048] (R2+R3)
  bf16_t* R4 = (bf16_t*)(ws + wbytes + 4*RB);    // Vcat / sb
  bf16_t* R5 = (bf16_t*)(ws + wbytes + 5*RB);    // Vt [NB][2048,2048]

  const int  Mc = NB * 2048;
  const dim3 blk(256);
  const dim3 gqkv(48, Mc / 128, 1);
  const dim3 gsc(32, 16, NB);
  const dim3 gpv(16, 16, NB);
  const dim3 go(16, Mc / 128, 1);
  const dim3 gtr(16, Mc / 64, 1);

  if (fullW) {
    for (int p = 0; p < 3; ++p)
      pack_w_kernel<<<1024, blk, 0, stream>>>(w_a[p], w_b[p],
          Wqkv + (size_t)(2*p)   * 2097152ull,
          Wqkv + (size_t)(2*p+1) * 2097152ull, neg_c2);
    pack_w_kernel<<<1024, blk, 0, stream>>>(w_a[3], w_b[3],
        Wo, Wo + 2097152ull, neg_c2);
  }

  for (int c = 0; c < 4 / NB; ++c) {
    const size_t xoff = (size_t)c * NB * 2097152ull;
    pack_x_kernel<<<Mc, blk, 0, stream>>>(xa + xoff, xb + xoff, R0, Mc * 256);

    if (!fullW)
      for (int p = 0; p < 3; ++p)
        pack_w_kernel<<<1024, blk, 0, stream>>>(w_a[p], w_b[p],
            Wqkv + (size_t)(2*p)   * 2097152ull,
            Wqkv + (size_t)(2*p+1) * 2097152ull, neg_c2);

    // fused QKV: [Mc,6144] = Xcat @ Wqkv^T, routed epilogue
    gemm_bt_kernel<0><<<gqkv, blk, 0, stream>>>(R0, Wqkv, 2048, 2048, 2048, 0, 0,
        R1, Kc, R4, b_a[0], b_b[0], b_a[1], b_b[1], b_a[2], b_b[2], neg_c2);

    // V transpose into R5 = per-batch [Va^T ; Vb^T]
    transpose_v_kernel<<<gtr, blk, 0, stream>>>(R4, R5, 0,    0);
    transpose_v_kernel<<<gtr, blk, 0, stream>>>(R4, R5, 1024, 1024);

    // fused scores: [2048,4096] per batch = Qcat_b @ Kc_b^T -> sa(R0), sb(R4)
    gemm_bt_kernel<1><<<gsc, blk, 0, stream>>>(R1, Kc, 2048, 2048, 2048, 4194304, 8388608,
        R0, R4, nullptr, nullptr, nullptr, nullptr, nullptr, nullptr, nullptr, 0.f);

    // magnitude + softmax -> bf16 attn (in-place over R0)
    softmax_mag_kernel<<<Mc, blk, 0, stream>>>(R0, R4, R0);

    // PV: [out_a|out_b] = attn @ Vt^T -> R1
    gemm_bt_kernel<2><<<gpv, blk, 0, stream>>>(R0, R5, 2048, 2048, 2048, 4194304, 4194304,
        R1, nullptr, nullptr, nullptr, nullptr, nullptr, nullptr, nullptr, nullptr, 0.f);

    // fused O projection -> fp32 out_a / out_b
    if (!fullW)
      pack_w_kernel<<<1024, blk, 0, stream>>>(w_a[3], w_b[3], Wo, Wo + 2097152ull, neg_c2);
    gemm_bt_kernel<3><<<go, blk, 0, stream>>>(R1, Wo, 2048, 2048, 2048, 0, 0,
        out + xoff, out + 8388608ull + xoff, nullptr,
        b_a[3], b_b[3], nullptr, nullptr, nullptr, nullptr, 0.f);
  }
}

// Round 4
// 606.388 us; speedup vs baseline: 1.3394x; 1.2765x over previous
//
#include <hip/hip_runtime.h>
#include <math.h>

typedef __bf16 bf16_t;
typedef __attribute__((ext_vector_type(4))) float f32x4;
typedef __attribute__((ext_vector_type(8))) __bf16 v8bf;
typedef __attribute__((ext_vector_type(4))) __bf16 v4bf;

#define GLOAD_LDS16(g, l)                                                     \
  __builtin_amdgcn_global_load_lds(                                           \
      (const __attribute__((address_space(1))) void*)(g),                     \
      (__attribute__((address_space(3))) void*)(l), 16, 0, 0)

// ---------------- diagnostic sentinel ----------------
__global__ void sentinel_kernel(float* o, float v) { o[0] = v; }

// ---------------- pack kernels ----------------
__global__ __launch_bounds__(256) void pack_x_kernel(
    const float* __restrict__ xa, const float* __restrict__ xb,
    bf16_t* __restrict__ xcat, int n4)
{
  int i = blockIdx.x * 256 + threadIdx.x;
  if (i >= n4) return;
  float4 a = reinterpret_cast<const float4*>(xa)[i];
  float4 b = reinterpret_cast<const float4*>(xb)[i];
  long e = (long)i * 4;
  long m = e >> 10;
  int  d = (int)(e & 1023);
  v4bf av = { (bf16_t)a.x, (bf16_t)a.y, (bf16_t)a.z, (bf16_t)a.w };
  v4bf bv = { (bf16_t)b.x, (bf16_t)b.y, (bf16_t)b.z, (bf16_t)b.w };
  *reinterpret_cast<v4bf*>(xcat + m * 2048 + d)        = av;
  *reinterpret_cast<v4bf*>(xcat + m * 2048 + 1024 + d) = bv;
}

// outA[n] = [wa[n,:] | j2*wb[n,:]] ; outB[n] = [wb[n,:] | wa[n,:]]
__global__ __launch_bounds__(256) void pack_w_kernel(
    const float* __restrict__ wa, const float* __restrict__ wb,
    bf16_t* __restrict__ outA, bf16_t* __restrict__ outB, float j2)
{
  int i = blockIdx.x * 256 + threadIdx.x;   // 0..262143, exact
  float4 a = reinterpret_cast<const float4*>(wa)[i];
  float4 b = reinterpret_cast<const float4*>(wb)[i];
  long e = (long)i * 4;
  long n = e >> 10;
  int  k = (int)(e & 1023);
  v4bf av = { (bf16_t)a.x, (bf16_t)a.y, (bf16_t)a.z, (bf16_t)a.w };
  v4bf bv = { (bf16_t)b.x, (bf16_t)b.y, (bf16_t)b.z, (bf16_t)b.w };
  v4bf jb = { (bf16_t)(j2*b.x), (bf16_t)(j2*b.y), (bf16_t)(j2*b.z), (bf16_t)(j2*b.w) };
  *reinterpret_cast<v4bf*>(outA + n * 2048 + k)        = av;
  *reinterpret_cast<v4bf*>(outA + n * 2048 + 1024 + k) = jb;
  *reinterpret_cast<v4bf*>(outB + n * 2048 + k)        = bv;
  *reinterpret_cast<v4bf*>(outB + n * 2048 + 1024 + k) = av;
}

// ---------------- 256x256 deep-pipelined bf16 GEMM, C = A @ B^T ----------------
// BK=32, 8 waves (2Mx4N), per-wave 128x64 out. 4-slot LDS ring (128 KiB),
// counted vmcnt(4) (T4), phase barriers + setprio (T3/T5), XOR-swizzled LDS (T2).
// EPI 0: QKV-routed (seg=col>>10). EPI 1: scores ->sa/sb. EPI 2: PV bf16.
// EPI 3: O-proj fp32 +bias.
template<int EPI>
__global__ __launch_bounds__(512) void gemm256_kernel(
    const bf16_t* __restrict__ A, const bf16_t* __restrict__ B,
    int K, long lda, long ldb, long bsA, long bsB,
    void* __restrict__ o0p, void* __restrict__ o1p, void* __restrict__ o2p,
    const float* __restrict__ bb0, const float* __restrict__ bb1,
    const float* __restrict__ bb2, const float* __restrict__ bb3,
    const float* __restrict__ bb4, const float* __restrict__ bb5,
    float scl)
{
  __shared__ __align__(16) bf16_t lds[65536];  // 4 slots x (A[256][32] | B[256][32])
  const int tid  = threadIdx.x;
  const int wid  = tid >> 6;
  const int lane = tid & 63;
  const int rr = lane & 15;
  const int kg = lane >> 4;
  const int wm = wid >> 2;        // 0..1  (M half)
  const int wn = wid & 3;         // 0..3  (N quarter)
  const long row0 = (long)blockIdx.y * 256;
  const long col0 = (long)blockIdx.x * 256;
  const int z = blockIdx.z;
  const bf16_t* Ab = A + (long)z * bsA + row0 * lda;
  const bf16_t* Bb = B + (long)z * bsB + col0 * ldb;

  // staging map: thread covers row rhat, 16B chunk (tid&3) of a [128][32el] half-tile.
  // LDS dest stays LINEAR; swizzle applied to the GLOBAL source column (rule #21).
  const int rhat = tid >> 2;
  const int scol = ((tid & 3) * 8) ^ (((rhat >> 1) & 3) << 3);
  const bf16_t* gA0 = Ab + (long)rhat * lda + scol;
  const bf16_t* gA1 = Ab + (long)(rhat + 128) * lda + scol;
  const bf16_t* gB0 = Bb + (long)rhat * ldb + scol;
  const bf16_t* gB1 = Bb + (long)(rhat + 128) * ldb + scol;
  const int dbase = wid * 512;    // wave-uniform element offset within a 4096-el half

#define STAGE_A0(t_) GLOAD_LDS16(gA0 + (long)(t_) * 32, lds + ((t_) & 3) * 16384 +         dbase)
#define STAGE_A1(t_) GLOAD_LDS16(gA1 + (long)(t_) * 32, lds + ((t_) & 3) * 16384 +  4096 + dbase)
#define STAGE_B0(t_) GLOAD_LDS16(gB0 + (long)(t_) * 32, lds + ((t_) & 3) * 16384 +  8192 + dbase)
#define STAGE_B1(t_) GLOAD_LDS16(gB1 + (long)(t_) * 32, lds + ((t_) & 3) * 16384 + 12288 + dbase)

  // ds_read offsets (elements), swizzle x = ((row>>1)&3)<<3 el; row&7 pattern -> bijective 1KiB read
  const int kq = (kg * 8) ^ (((rr >> 1) & 3) << 3);
  const int abase = (wm * 128 + rr) * 32 + kq;
  const int bbase = 8192 + (wn * 64 + rr) * 32 + kq;

  f32x4 acc[8][4];
#pragma unroll
  for (int i = 0; i < 8; ++i)
#pragma unroll
    for (int j = 0; j < 4; ++j) acc[i][j] = (f32x4){0.f, 0.f, 0.f, 0.f};

  const int T = K >> 5;   // BK=32

  // prologue: stage tiles 0 and 1; guarantee tile 0 landed (all waves) via vmcnt+barrier
  STAGE_A0(0); STAGE_A1(0); STAGE_B0(0); STAGE_B1(0);
  STAGE_A0(1); STAGE_A1(1); STAGE_B0(1); STAGE_B1(1);
  asm volatile("s_waitcnt vmcnt(4)" ::: "memory");
  __builtin_amdgcn_sched_barrier(0);
  __builtin_amdgcn_s_barrier();

  for (int t = 0; t < T; ++t) {
    const int slotE = (t & 3) * 16384;
    const bool pf = (t + 2) < T;
    v8bf ar[4], br[4];
    // ---- phase A (M-frags 0-3): 8 ds_read_b128 + 2 stage issues ----
#pragma unroll
    for (int j = 0; j < 4; ++j)
      br[j] = *reinterpret_cast<const v8bf*>(lds + slotE + bbase + j * 512);
#pragma unroll
    for (int i = 0; i < 4; ++i)
      ar[i] = *reinterpret_cast<const v8bf*>(lds + slotE + abase + i * 512);
    if (pf) { STAGE_A0(t + 2); STAGE_A1(t + 2); }
    __builtin_amdgcn_s_barrier();
    __builtin_amdgcn_s_setprio(1);
#pragma unroll
    for (int i = 0; i < 4; ++i)
#pragma unroll
      for (int j = 0; j < 4; ++j)
        acc[i][j] = __builtin_amdgcn_mfma_f32_16x16x32_bf16(ar[i], br[j], acc[i][j], 0, 0, 0);
    __builtin_amdgcn_s_setprio(0);
    __builtin_amdgcn_s_barrier();
    // ---- phase B (M-frags 4-7): 4 ds_read_b128 + 2 stage issues ----
#pragma unroll
    for (int i = 0; i < 4; ++i)
      ar[i] = *reinterpret_cast<const v8bf*>(lds + slotE + abase + (4 + i) * 512);
    if (pf) { STAGE_B0(t + 2); STAGE_B1(t + 2); }
    __builtin_amdgcn_s_barrier();
    __builtin_amdgcn_s_setprio(1);
#pragma unroll
    for (int i = 0; i < 4; ++i)
#pragma unroll
      for (int j = 0; j < 4; ++j)
        acc[4 + i][j] = __builtin_amdgcn_mfma_f32_16x16x32_bf16(ar[i], br[j], acc[4 + i][j], 0, 0, 0);
    __builtin_amdgcn_s_setprio(0);
    // counted wait (T4): all but 4 newest loads landed => tile t+1 fully resident
    if (pf) { asm volatile("s_waitcnt vmcnt(4)" ::: "memory"); }
    else    { asm volatile("s_waitcnt vmcnt(0)" ::: "memory"); }
    __builtin_amdgcn_sched_barrier(0);
    __builtin_amdgcn_s_barrier();
  }
#undef STAGE_A0
#undef STAGE_A1
#undef STAGE_B0
#undef STAGE_B1

  // epilogue: C/D layout col=lane&15, row=(lane>>4)*4+reg  [m89-verified]
#pragma unroll
  for (int ii = 0; ii < 8; ++ii) {
    const long mrow = row0 + wm * 128 + ii * 16 + kg * 4;
#pragma unroll
    for (int j = 0; j < 4; ++j) {
      const long col = col0 + wn * 64 + j * 16 + rr;
#pragma unroll
      for (int r2 = 0; r2 < 4; ++r2) {
        const float v = acc[ii][j][r2];
        const long row = mrow + r2;
        if constexpr (EPI == 0) {
          const int  seg = (int)(col >> 10);   // uniform per block (256 | 1024)
          const long c   = col & 1023;
          bf16_t* Q  = (bf16_t*)o0p;
          bf16_t* Kc = (bf16_t*)o1p;
          bf16_t* Vc = (bf16_t*)o2p;
          const long kbase = (row >> 11) * 8388608 + (row & 2047) * 2048;
          switch (seg) {
            case 0: Q[row * 2048 + c]        = (bf16_t)((v + bb0[c]) * 0.03125f); break;
            case 1: Q[row * 2048 + 1024 + c] = (bf16_t)((v + bb1[c]) * 0.03125f); break;
            case 2: { const float w = v + bb2[c];
                      Kc[kbase + c]                   = (bf16_t)w;          // K1 = [Ka | .]
                      Kc[kbase + 4194304 + 1024 + c]  = (bf16_t)w;          // K2 = [. | Ka]
                    } break;
            case 3: { const float w = v + bb3[c];
                      Kc[kbase + 4194304 + c]         = (bf16_t)w;          // K2 = [Kb | .]
                      Kc[kbase + 1024 + c]            = (bf16_t)(scl * w);  // K1 = [. | -c2*Kb]
                    } break;
            case 4: Vc[row * 2048 + c]        = (bf16_t)(v + bb4[c]); break;
            default: Vc[row * 2048 + 1024 + c] = (bf16_t)(v + bb5[c]); break;
          }
        } else if constexpr (EPI == 1) {
          const int  seg = (int)(col >> 11);
          const long c   = col & 2047;
          bf16_t* dst = seg ? (bf16_t*)o1p : (bf16_t*)o0p;
          dst[(long)z * 4194304 + row * 2048 + c] = (bf16_t)v;
        } else if constexpr (EPI == 2) {
          ((bf16_t*)o0p)[(long)z * 4194304 + row * 2048 + col] = (bf16_t)v;
        } else {
          const int  seg = (int)(col >> 10);
          const long c   = col & 1023;
          float* dst = seg ? (float*)o1p : (float*)o0p;
          const float bv = seg ? bb1[c] : bb0[c];
          dst[row * 1024 + c] = v + bv;
        }
      }
    }
  }
}

// ---------------- V transpose ----------------
__global__ __launch_bounds__(256) void transpose_v_kernel(
    const bf16_t* __restrict__ src, bf16_t* __restrict__ dst,
    int srcoff, int dstoff)
{
  __shared__ bf16_t t[64][65];
  const int tid = threadIdx.x;
  const long c0 = (long)blockIdx.x * 64;
  const long g0 = (long)blockIdx.y * 64;
#pragma unroll
  for (int it = 0; it < 16; ++it) {
    int idx = it * 256 + tid;
    int r = idx >> 6, c = idx & 63;
    t[r][c] = src[(g0 + r) * 2048 + srcoff + c0 + c];
  }
  __syncthreads();
  const long b  = g0 >> 11;
  const long t0 = g0 & 2047;
#pragma unroll
  for (int it = 0; it < 16; ++it) {
    int idx = it * 256 + tid;
    int nr = idx >> 6, tc = idx & 63;
    dst[b * 4194304 + (dstoff + c0 + nr) * 2048 + t0 + tc] = t[tc][nr];
  }
}

// ---------------- magnitude + softmax ----------------
__global__ __launch_bounds__(256) void softmax_mag_kernel(
    const bf16_t* __restrict__ sa, const bf16_t* __restrict__ sb,
    bf16_t* __restrict__ attn)
{
  const int tid = threadIdx.x;
  const long base = (long)blockIdx.x * 2048;
  v4bf a0 = *reinterpret_cast<const v4bf*>(sa + base + tid * 4);
  v4bf a1 = *reinterpret_cast<const v4bf*>(sa + base + 1024 + tid * 4);
  v4bf b0 = *reinterpret_cast<const v4bf*>(sb + base + tid * 4);
  v4bf b1 = *reinterpret_cast<const v4bf*>(sb + base + 1024 + tid * 4);
  float r[8];
#pragma unroll
  for (int k = 0; k < 4; ++k) {
    float x = (float)a0[k], y = (float)b0[k];
    r[k] = sqrtf(x * x + y * y);
  }
#pragma unroll
  for (int k = 0; k < 4; ++k) {
    float x = (float)a1[k], y = (float)b1[k];
    r[4 + k] = sqrtf(x * x + y * y);
  }
  float m = r[0];
#pragma unroll
  for (int k = 1; k < 8; ++k) m = fmaxf(m, r[k]);
#pragma unroll
  for (int off = 32; off > 0; off >>= 1) m = fmaxf(m, __shfl_xor(m, off));
  __shared__ float red[8];
  if ((tid & 63) == 0) red[tid >> 6] = m;
  __syncthreads();
  m = fmaxf(fmaxf(red[0], red[1]), fmaxf(red[2], red[3]));
  float p[8], s = 0.f;
#pragma unroll
  for (int k = 0; k < 8; ++k) { p[k] = __expf(r[k] - m); s += p[k]; }
#pragma unroll
  for (int off = 32; off > 0; off >>= 1) s += __shfl_xor(s, off);
  if ((tid & 63) == 0) red[4 + (tid >> 6)] = s;
  __syncthreads();
  const float inv = 1.f / (red[4] + red[5] + red[6] + red[7]);
  v4bf o0 = { (bf16_t)(p[0]*inv), (bf16_t)(p[1]*inv), (bf16_t)(p[2]*inv), (bf16_t)(p[3]*inv) };
  v4bf o1 = { (bf16_t)(p[4]*inv), (bf16_t)(p[5]*inv), (bf16_t)(p[6]*inv), (bf16_t)(p[7]*inv) };
  *reinterpret_cast<v4bf*>(attn + base + tid * 4)        = o0;
  *reinterpret_cast<v4bf*>(attn + base + 1024 + tid * 4) = o1;
}

// ---------------- host ----------------
extern "C" void kernel_launch(void* const* d_in, const int* in_sizes, int n_in,
                              void* d_out, int out_size, void* d_ws, size_t ws_size,
                              hipStream_t stream)
{
  (void)in_sizes; (void)n_in; (void)out_size;
  const float* xa = (const float*)d_in[0];
  const float* xb = (const float*)d_in[1];
  const float *w_a[4], *w_b[4], *b_a[4], *b_b[4];
  for (int p = 0; p < 4; ++p) {
    w_a[p] = (const float*)d_in[2 + p*4 + 0];
    w_b[p] = (const float*)d_in[2 + p*4 + 1];
    b_a[p] = (const float*)d_in[2 + p*4 + 2];
    b_b[p] = (const float*)d_in[2 + p*4 + 3];
  }
  float* out = (float*)d_out;
  const float neg_c2 = (float)(-cos(2.0));

  // ---- adaptive workspace tiers (identical thresholds to passing rounds) ----
  const size_t WFULL = 33554432ull;   // 8 weight slots of [1024,2048] bf16
  const size_t WQKV  = 25165824ull;   // 6 slots (low tier: O re-packed over QKV)
  int NB = 0; bool fullW = true;
  if      (ws_size >= WFULL + 6ull * 4ull * 8388608ull) NB = 4;               // 224 MiB
  else if (ws_size >= WFULL + 6ull * 2ull * 8388608ull) NB = 2;               // 128 MiB
  else if (ws_size >= WFULL + 6ull * 1ull * 8388608ull) NB = 1;               //  80 MiB
  else if (ws_size >= WQKV  + 6ull * 1ull * 8388608ull) { NB = 1; fullW = false; } // 72 MiB
  else { sentinel_kernel<<<1, 1, 0, stream>>>(out, (float)ws_size); return; }

  char* ws = (char*)d_ws;
  const size_t wbytes = fullW ? WFULL : WQKV;
  const size_t RB = (size_t)NB * 8388608ull;
  bf16_t* Wqkv = (bf16_t*)ws;                            // 6 x [1024,2048]
  bf16_t* Wo   = fullW ? (bf16_t*)(ws + WQKV) : Wqkv;    // 2 x [1024,2048]
  bf16_t* R0 = (bf16_t*)(ws + wbytes);           // Xcat / sa / attn
  bf16_t* R1 = (bf16_t*)(ws + wbytes + 1*RB);    // Qcat / outc
  bf16_t* Kc = (bf16_t*)(ws + wbytes + 2*RB);    // [NB][2][2048][2048]
  bf16_t* R4 = (bf16_t*)(ws + wbytes + 4*RB);    // Vcat / sb
  bf16_t* R5 = (bf16_t*)(ws + wbytes + 5*RB);    // Vt [NB][2048,2048]

  const int  Mc = NB * 2048;
  const dim3 blk(256);
  const dim3 blk512(512);
  const dim3 gqkv(24, Mc / 256, 1);
  const dim3 gsc(16, 8, NB);
  const dim3 gpv(8, 8, NB);
  const dim3 go(8, Mc / 256, 1);
  const dim3 gtr(16, Mc / 64, 1);

  if (fullW) {
    for (int p = 0; p < 3; ++p)
      pack_w_kernel<<<1024, blk, 0, stream>>>(w_a[p], w_b[p],
          Wqkv + (size_t)(2*p)   * 2097152ull,
          Wqkv + (size_t)(2*p+1) * 2097152ull, neg_c2);
    pack_w_kernel<<<1024, blk, 0, stream>>>(w_a[3], w_b[3],
        Wo, Wo + 2097152ull, neg_c2);
  }

  for (int c = 0; c < 4 / NB; ++c) {
    const size_t xoff = (size_t)c * NB * 2097152ull;
    pack_x_kernel<<<Mc, blk, 0, stream>>>(xa + xoff, xb + xoff, R0, Mc * 256);

    if (!fullW)
      for (int p = 0; p < 3; ++p)
        pack_w_kernel<<<1024, blk, 0, stream>>>(w_a[p], w_b[p],
            Wqkv + (size_t)(2*p)   * 2097152ull,
            Wqkv + (size_t)(2*p+1) * 2097152ull, neg_c2);

    // fused QKV: [Mc,6144] = Xcat @ Wqkv^T, routed epilogue
    gemm256_kernel<0><<<gqkv, blk512, 0, stream>>>(R0, Wqkv, 2048, 2048, 2048, 0, 0,
        R1, Kc, R4, b_a[0], b_b[0], b_a[1], b_b[1], b_a[2], b_b[2], neg_c2);

    // V transpose into R5 = per-batch [Va^T ; Vb^T]
    transpose_v_kernel<<<gtr, blk, 0, stream>>>(R4, R5, 0,    0);
    transpose_v_kernel<<<gtr, blk, 0, stream>>>(R4, R5, 1024, 1024);

    // fused scores: [2048,4096] per batch = Qcat_b @ Kc_b^T -> sa(R0), sb(R4)
    gemm256_kernel<1><<<gsc, blk512, 0, stream>>>(R1, Kc, 2048, 2048, 2048, 4194304, 8388608,
        R0, R4, nullptr, nullptr, nullptr, nullptr, nullptr, nullptr, nullptr, 0.f);

    // magnitude + softmax -> bf16 attn (in-place over R0)
    softmax_mag_kernel<<<Mc, blk, 0, stream>>>(R0, R4, R0);

    // PV: [out_a|out_b] = attn @ Vt^T -> R1
    gemm256_kernel<2><<<gpv, blk512, 0, stream>>>(R0, R5, 2048, 2048, 2048, 4194304, 4194304,
        R1, nullptr, nullptr, nullptr, nullptr, nullptr, nullptr, nullptr, nullptr, 0.f);

    // fused O projection -> fp32 out_a / out_b
    if (!fullW)
      pack_w_kernel<<<1024, blk, 0, stream>>>(w_a[3], w_b[3], Wo, Wo + 2097152ull, neg_c2);
    gemm256_kernel<3><<<go, blk512, 0, stream>>>(R1, Wo, 2048, 2048, 2048, 0, 0,
        out + xoff, out + 8388608ull + xoff, nullptr,
        b_a[3], b_b[3], nullptr, nullptr, nullptr, nullptr, 0.f);
  }
}

// Round 6
// 564.947 us; speedup vs baseline: 1.4377x; 1.0734x over previous
//
#include <hip/hip_runtime.h>
#include <math.h>

typedef __bf16 bf16_t;
typedef __attribute__((ext_vector_type(4))) float f32x4;
typedef __attribute__((ext_vector_type(8))) __bf16 v8bf;
typedef __attribute__((ext_vector_type(4))) __bf16 v4bf;

// offset=0 ALWAYS: LDS-DMA offset imm shifts the LDS destination too (R5 post-mortem).
#define GLLDS(g, l)                                                           \
  __builtin_amdgcn_global_load_lds(                                           \
      (const __attribute__((address_space(1))) void*)(g),                     \
      (__attribute__((address_space(3))) void*)(l), 16, 0, 0)
// opaque pointer tie: prevents the backend from folding constant pointer
// steps back into the LDS-DMA offset immediate.
#define OPQ(p) asm volatile("" : "+v"(p))

// ---------------- diagnostic sentinel ----------------
__global__ void sentinel_kernel(float* o, float v) { o[0] = v; }

// ---------------- pack kernels ----------------
__global__ __launch_bounds__(256) void pack_x_kernel(
    const float* __restrict__ xa, const float* __restrict__ xb,
    bf16_t* __restrict__ xcat, int n4)
{
  int i = blockIdx.x * 256 + threadIdx.x;
  if (i >= n4) return;
  float4 a = reinterpret_cast<const float4*>(xa)[i];
  float4 b = reinterpret_cast<const float4*>(xb)[i];
  long e = (long)i * 4;
  long m = e >> 10;
  int  d = (int)(e & 1023);
  v4bf av = { (bf16_t)a.x, (bf16_t)a.y, (bf16_t)a.z, (bf16_t)a.w };
  v4bf bv = { (bf16_t)b.x, (bf16_t)b.y, (bf16_t)b.z, (bf16_t)b.w };
  *reinterpret_cast<v4bf*>(xcat + m * 2048 + d)        = av;
  *reinterpret_cast<v4bf*>(xcat + m * 2048 + 1024 + d) = bv;
}

// outA[n] = [wa[n,:] | j2*wb[n,:]] ; outB[n] = [wb[n,:] | wa[n,:]]
__global__ __launch_bounds__(256) void pack_w_kernel(
    const float* __restrict__ wa, const float* __restrict__ wb,
    bf16_t* __restrict__ outA, bf16_t* __restrict__ outB, float j2)
{
  int i = blockIdx.x * 256 + threadIdx.x;   // 0..262143, exact
  float4 a = reinterpret_cast<const float4*>(wa)[i];
  float4 b = reinterpret_cast<const float4*>(wb)[i];
  long e = (long)i * 4;
  long n = e >> 10;
  int  k = (int)(e & 1023);
  v4bf av = { (bf16_t)a.x, (bf16_t)a.y, (bf16_t)a.z, (bf16_t)a.w };
  v4bf bv = { (bf16_t)b.x, (bf16_t)b.y, (bf16_t)b.z, (bf16_t)b.w };
  v4bf jb = { (bf16_t)(j2*b.x), (bf16_t)(j2*b.y), (bf16_t)(j2*b.z), (bf16_t)(j2*b.w) };
  *reinterpret_cast<v4bf*>(outA + n * 2048 + k)        = av;
  *reinterpret_cast<v4bf*>(outA + n * 2048 + 1024 + k) = jb;
  *reinterpret_cast<v4bf*>(outB + n * 2048 + k)        = bv;
  *reinterpret_cast<v4bf*>(outB + n * 2048 + 1024 + k) = av;
}

// ---------------- 256x256 pipelined bf16 GEMM, C = A @ B^T ----------------
// BK=32, 8 waves (2Mx4N), per-wave 128x64. 4-slot LDS ring (128 KiB),
// ONE barrier per K-tile (slot-disjointness: tile t reads slot t&3, stages
// slot (t+2)&3; adjacent-tile lockstep keeps all pairs disjoint), counted
// vmcnt(4) (T4), setprio (T5), XOR-swizzled LDS (T2), K-loop unrolled x4
// so LDS slot offsets are immediates. Staging global addrs are rolling
// pointers (+32 el/tile) with opaque ties; LDS-DMA offset imm stays 0.
// EPI 0: QKV-routed. EPI 1: scores ->sa/sb. EPI 2: PV bf16. EPI 3: O fp32.
template<int EPI>
__global__ __launch_bounds__(512) void gemm256_kernel(
    const bf16_t* __restrict__ A, const bf16_t* __restrict__ B,
    int K, long lda, long ldb, long bsA, long bsB,
    void* __restrict__ o0p, void* __restrict__ o1p, void* __restrict__ o2p,
    const float* __restrict__ bb0, const float* __restrict__ bb1,
    const float* __restrict__ bb2, const float* __restrict__ bb3,
    const float* __restrict__ bb4, const float* __restrict__ bb5,
    float scl)
{
  __shared__ __align__(16) bf16_t lds[65536];  // 4 slots x (A[256][32] | B[256][32])
  const int tid  = threadIdx.x;
  const int wid  = tid >> 6;
  const int lane = tid & 63;
  const int rr = lane & 15;
  const int kg = lane >> 4;
  const int wm = wid >> 2;
  const int wn = wid & 3;

  // XCD-aware bijective swizzle (all grids have nwg % 8 == 0)
  int flat = blockIdx.y * gridDim.x + blockIdx.x;
  const int nwg = gridDim.x * gridDim.y;
  flat = (flat & 7) * (nwg >> 3) + (flat >> 3);
  const int bx = flat % gridDim.x;
  const int by = flat / gridDim.x;
  const long row0 = (long)by * 256;
  const long col0 = (long)bx * 256;
  const int z = blockIdx.z;
  const bf16_t* Ab = A + (long)z * bsA + row0 * lda;
  const bf16_t* Bb = B + (long)z * bsB + col0 * ldb;

  // staging: thread -> row rhat, 16B chunk (tid&3); LINEAR LDS dest,
  // swizzle applied to GLOBAL source column (rule #21). [validated R4]
  const int rhat = tid >> 2;
  const int scol = ((tid & 3) * 8) ^ (((rhat >> 1) & 3) << 3);
  const bf16_t* gA0 = Ab + (long)rhat * lda + scol;
  const bf16_t* gA1 = Ab + (long)(rhat + 128) * lda + scol;
  const bf16_t* gB0 = Bb + (long)rhat * ldb + scol;
  const bf16_t* gB1 = Bb + (long)(rhat + 128) * ldb + scol;
  const int dbase = wid * 512;   // wave-uniform element offset in a 4096-el quarter

  // ds_read bases (elements); swizzle identical to R4 [validated]
  const int kq = (kg * 8) ^ (((rr >> 1) & 3) << 3);
  const bf16_t* rdA  = lds + (wm * 128 + rr) * 32 + kq;          // slots 0,1
  const bf16_t* rdB  = lds + 8192 + (wn * 64 + rr) * 32 + kq;
  const bf16_t* rdA2 = rdA + 32768;                              // slots 2,3
  const bf16_t* rdB2 = rdB + 32768;

  f32x4 acc[8][4];
#pragma unroll
  for (int i = 0; i < 8; ++i)
#pragma unroll
    for (int j = 0; j < 4; ++j) acc[i][j] = (f32x4){0.f, 0.f, 0.f, 0.f};

  const int T = K >> 5;   // BK=32; K=2048 -> T=64 (T%4==0, T>=8)

  // rolling staging pointers (advance 32 el per staged tile, opaque each step)
  const bf16_t* sA0 = gA0;
  const bf16_t* sA1 = gA1;
  const bf16_t* sB0 = gB0;
  const bf16_t* sB1 = gB1;

  // prologue: stage tile 0 (slot 0) and tile 1 (slot 1), offset imm always 0
  GLLDS(sA0, lds + dbase);
  GLLDS(sA1, lds + 4096 + dbase);
  GLLDS(sB0, lds + 8192 + dbase);
  GLLDS(sB1, lds + 12288 + dbase);
  sA0 += 32; sA1 += 32; sB0 += 32; sB1 += 32;
  OPQ(sA0); OPQ(sA1); OPQ(sB0); OPQ(sB1);
  GLLDS(sA0, lds + 16384 + dbase);
  GLLDS(sA1, lds + 16384 + 4096 + dbase);
  GLLDS(sB0, lds + 16384 + 8192 + dbase);
  GLLDS(sB1, lds + 16384 + 12288 + dbase);
  sA0 += 32; sA1 += 32; sB0 += 32; sB1 += 32;
  OPQ(sA0); OPQ(sA1); OPQ(sB0); OPQ(sB1);
  asm volatile("s_waitcnt vmcnt(4)" ::: "memory");
  __builtin_amdgcn_sched_barrier(0);
  __builtin_amdgcn_s_barrier();

  // One tile: reads (slot U) + stage tile t+2 (slot (U+2)&3) + 32 MFMA,
  // single tile-end vmcnt+barrier. U is a literal 0..3.
#define TILE_BODY(U, PF)                                                       \
  {                                                                            \
    const bf16_t* ra_ = ((U) < 2) ? rdA : rdA2;                                \
    const bf16_t* rb_ = ((U) < 2) ? rdB : rdB2;                                \
    v8bf ar[4], br[4], ar2[4];                                                 \
    _Pragma("unroll")                                                          \
    for (int j = 0; j < 4; ++j)                                                \
      br[j] = *reinterpret_cast<const v8bf*>(rb_ + ((U) & 1) * 16384 + j * 512); \
    _Pragma("unroll")                                                          \
    for (int i = 0; i < 4; ++i)                                                \
      ar[i] = *reinterpret_cast<const v8bf*>(ra_ + ((U) & 1) * 16384 + i * 512); \
    if (PF) {                                                                  \
      GLLDS(sA0, lds + (((U) + 2) & 3) * 16384 + dbase);                       \
      GLLDS(sA1, lds + (((U) + 2) & 3) * 16384 + 4096 + dbase);                \
    }                                                                          \
    __builtin_amdgcn_s_setprio(1);                                             \
    _Pragma("unroll")                                                          \
    for (int i = 0; i < 4; ++i)                                                \
      _Pragma("unroll")                                                        \
      for (int j = 0; j < 4; ++j)                                              \
        acc[i][j] = __builtin_amdgcn_mfma_f32_16x16x32_bf16(ar[i], br[j], acc[i][j], 0, 0, 0); \
    _Pragma("unroll")                                                          \
    for (int i = 0; i < 4; ++i)                                                \
      ar2[i] = *reinterpret_cast<const v8bf*>(ra_ + ((U) & 1) * 16384 + (4 + i) * 512); \
    if (PF) {                                                                  \
      GLLDS(sB0, lds + (((U) + 2) & 3) * 16384 + 8192 + dbase);                \
      GLLDS(sB1, lds + (((U) + 2) & 3) * 16384 + 12288 + dbase);               \
      sA0 += 32; sA1 += 32; sB0 += 32; sB1 += 32;                              \
      OPQ(sA0); OPQ(sA1); OPQ(sB0); OPQ(sB1);                                  \
    }                                                                          \
    _Pragma("unroll")                                                          \
    for (int i = 0; i < 4; ++i)                                                \
      _Pragma("unroll")                                                        \
      for (int j = 0; j < 4; ++j)                                              \
        acc[4 + i][j] = __builtin_amdgcn_mfma_f32_16x16x32_bf16(ar2[i], br[j], acc[4 + i][j], 0, 0, 0); \
    __builtin_amdgcn_s_setprio(0);                                             \
    if (PF) { asm volatile("s_waitcnt vmcnt(4)" ::: "memory"); }               \
    else    { asm volatile("s_waitcnt vmcnt(0)" ::: "memory"); }               \
    __builtin_amdgcn_sched_barrier(0);                                         \
    __builtin_amdgcn_s_barrier();                                              \
  }

  // main: tiles 0..T-5 with prefetch
  for (int tb = 0; tb < T - 4; tb += 4) {
    TILE_BODY(0, 1)
    TILE_BODY(1, 1)
    TILE_BODY(2, 1)
    TILE_BODY(3, 1)
  }
  // tail: tiles T-4..T-1 (slots 0..3); stage tiles T-2, T-1 in first two
  TILE_BODY(0, 1)
  TILE_BODY(1, 1)
  TILE_BODY(2, 0)
  TILE_BODY(3, 0)
#undef TILE_BODY

  // epilogue: C/D layout col=lane&15, row=(lane>>4)*4+reg  [m89-verified]
#pragma unroll
  for (int ii = 0; ii < 8; ++ii) {
    const long mrow = row0 + wm * 128 + ii * 16 + kg * 4;
#pragma unroll
    for (int j = 0; j < 4; ++j) {
      const long col = col0 + wn * 64 + j * 16 + rr;
#pragma unroll
      for (int r2 = 0; r2 < 4; ++r2) {
        const float v = acc[ii][j][r2];
        const long row = mrow + r2;
        if constexpr (EPI == 0) {
          const int  seg = (int)(col >> 10);   // uniform per block (256 | 1024)
          const long c   = col & 1023;
          bf16_t* Q  = (bf16_t*)o0p;
          bf16_t* Kc = (bf16_t*)o1p;
          bf16_t* Vc = (bf16_t*)o2p;
          const long kbase = (row >> 11) * 8388608 + (row & 2047) * 2048;
          switch (seg) {
            case 0: Q[row * 2048 + c]        = (bf16_t)((v + bb0[c]) * 0.03125f); break;
            case 1: Q[row * 2048 + 1024 + c] = (bf16_t)((v + bb1[c]) * 0.03125f); break;
            case 2: { const float w = v + bb2[c];
                      Kc[kbase + c]                   = (bf16_t)w;          // K1 = [Ka | .]
                      Kc[kbase + 4194304 + 1024 + c]  = (bf16_t)w;          // K2 = [. | Ka]
                    } break;
            case 3: { const float w = v + bb3[c];
                      Kc[kbase + 4194304 + c]         = (bf16_t)w;          // K2 = [Kb | .]
                      Kc[kbase + 1024 + c]            = (bf16_t)(scl * w);  // K1 = [. | -c2*Kb]
                    } break;
            case 4: Vc[row * 2048 + c]        = (bf16_t)(v + bb4[c]); break;
            default: Vc[row * 2048 + 1024 + c] = (bf16_t)(v + bb5[c]); break;
          }
        } else if constexpr (EPI == 1) {
          const int  seg = (int)(col >> 11);
          const long c   = col & 2047;
          bf16_t* dst = seg ? (bf16_t*)o1p : (bf16_t*)o0p;
          dst[(long)z * 4194304 + row * 2048 + c] = (bf16_t)v;
        } else if constexpr (EPI == 2) {
          ((bf16_t*)o0p)[(long)z * 4194304 + row * 2048 + col] = (bf16_t)v;
        } else {
          const int  seg = (int)(col >> 10);
          const long c   = col & 1023;
          float* dst = seg ? (float*)o1p : (float*)o0p;
          const float bv = seg ? bb1[c] : bb0[c];
          dst[row * 1024 + c] = v + bv;
        }
      }
    }
  }
}

// ---------------- V transpose ----------------
__global__ __launch_bounds__(256) void transpose_v_kernel(
    const bf16_t* __restrict__ src, bf16_t* __restrict__ dst,
    int srcoff, int dstoff)
{
  __shared__ bf16_t t[64][65];
  const int tid = threadIdx.x;
  const long c0 = (long)blockIdx.x * 64;
  const long g0 = (long)blockIdx.y * 64;
#pragma unroll
  for (int it = 0; it < 16; ++it) {
    int idx = it * 256 + tid;
    int r = idx >> 6, c = idx & 63;
    t[r][c] = src[(g0 + r) * 2048 + srcoff + c0 + c];
  }
  __syncthreads();
  const long b  = g0 >> 11;
  const long t0 = g0 & 2047;
#pragma unroll
  for (int it = 0; it < 16; ++it) {
    int idx = it * 256 + tid;
    int nr = idx >> 6, tc = idx & 63;
    dst[b * 4194304 + (dstoff + c0 + nr) * 2048 + t0 + tc] = t[tc][nr];
  }
}

// ---------------- magnitude + softmax ----------------
__global__ __launch_bounds__(256) void softmax_mag_kernel(
    const bf16_t* __restrict__ sa, const bf16_t* __restrict__ sb,
    bf16_t* __restrict__ attn)
{
  const int tid = threadIdx.x;
  const long base = (long)blockIdx.x * 2048;
  v4bf a0 = *reinterpret_cast<const v4bf*>(sa + base + tid * 4);
  v4bf a1 = *reinterpret_cast<const v4bf*>(sa + base + 1024 + tid * 4);
  v4bf b0 = *reinterpret_cast<const v4bf*>(sb + base + tid * 4);
  v4bf b1 = *reinterpret_cast<const v4bf*>(sb + base + 1024 + tid * 4);
  float r[8];
#pragma unroll
  for (int k = 0; k < 4; ++k) {
    float x = (float)a0[k], y = (float)b0[k];
    r[k] = sqrtf(x * x + y * y);
  }
#pragma unroll
  for (int k = 0; k < 4; ++k) {
    float x = (float)a1[k], y = (float)b1[k];
    r[4 + k] = sqrtf(x * x + y * y);
  }
  float m = r[0];
#pragma unroll
  for (int k = 1; k < 8; ++k) m = fmaxf(m, r[k]);
#pragma unroll
  for (int off = 32; off > 0; off >>= 1) m = fmaxf(m, __shfl_xor(m, off));
  __shared__ float red[8];
  if ((tid & 63) == 0) red[tid >> 6] = m;
  __syncthreads();
  m = fmaxf(fmaxf(red[0], red[1]), fmaxf(red[2], red[3]));
  float p[8], s = 0.f;
#pragma unroll
  for (int k = 0; k < 8; ++k) { p[k] = __expf(r[k] - m); s += p[k]; }
#pragma unroll
  for (int off = 32; off > 0; off >>= 1) s += __shfl_xor(s, off);
  if ((tid & 63) == 0) red[4 + (tid >> 6)] = s;
  __syncthreads();
  const float inv = 1.f / (red[4] + red[5] + red[6] + red[7]);
  v4bf o0 = { (bf16_t)(p[0]*inv), (bf16_t)(p[1]*inv), (bf16_t)(p[2]*inv), (bf16_t)(p[3]*inv) };
  v4bf o1 = { (bf16_t)(p[4]*inv), (bf16_t)(p[5]*inv), (bf16_t)(p[6]*inv), (bf16_t)(p[7]*inv) };
  *reinterpret_cast<v4bf*>(attn + base + tid * 4)        = o0;
  *reinterpret_cast<v4bf*>(attn + base + 1024 + tid * 4) = o1;
}

// ---------------- host ----------------
extern "C" void kernel_launch(void* const* d_in, const int* in_sizes, int n_in,
                              void* d_out, int out_size, void* d_ws, size_t ws_size,
                              hipStream_t stream)
{
  (void)in_sizes; (void)n_in; (void)out_size;
  const float* xa = (const float*)d_in[0];
  const float* xb = (const float*)d_in[1];
  const float *w_a[4], *w_b[4], *b_a[4], *b_b[4];
  for (int p = 0; p < 4; ++p) {
    w_a[p] = (const float*)d_in[2 + p*4 + 0];
    w_b[p] = (const float*)d_in[2 + p*4 + 1];
    b_a[p] = (const float*)d_in[2 + p*4 + 2];
    b_b[p] = (const float*)d_in[2 + p*4 + 3];
  }
  float* out = (float*)d_out;
  const float neg_c2 = (float)(-cos(2.0));

  // ---- adaptive workspace tiers (identical thresholds to passing rounds) ----
  const size_t WFULL = 33554432ull;   // 8 weight slots of [1024,2048] bf16
  const size_t WQKV  = 25165824ull;   // 6 slots (low tier: O re-packed over QKV)
  int NB = 0; bool fullW = true;
  if      (ws_size >= WFULL + 6ull * 4ull * 8388608ull) NB = 4;               // 224 MiB
  else if (ws_size >= WFULL + 6ull * 2ull * 8388608ull) NB = 2;               // 128 MiB
  else if (ws_size >= WFULL + 6ull * 1ull * 8388608ull) NB = 1;               //  80 MiB
  else if (ws_size >= WQKV  + 6ull * 1ull * 8388608ull) { NB = 1; fullW = false; } // 72 MiB
  else { sentinel_kernel<<<1, 1, 0, stream>>>(out, (float)ws_size); return; }

  char* ws = (char*)d_ws;
  const size_t wbytes = fullW ? WFULL : WQKV;
  const size_t RB = (size_t)NB * 8388608ull;
  bf16_t* Wqkv = (bf16_t*)ws;                            // 6 x [1024,2048]
  bf16_t* Wo   = fullW ? (bf16_t*)(ws + WQKV) : Wqkv;    // 2 x [1024,2048]
  bf16_t* R0 = (bf16_t*)(ws + wbytes);           // Xcat / sa / attn
  bf16_t* R1 = (bf16_t*)(ws + wbytes + 1*RB);    // Qcat / outc
  bf16_t* Kc = (bf16_t*)(ws + wbytes + 2*RB);    // [NB][2][2048][2048]
  bf16_t* R4 = (bf16_t*)(ws + wbytes + 4*RB);    // Vcat / sb
  bf16_t* R5 = (bf16_t*)(ws + wbytes + 5*RB);    // Vt [NB][2048,2048]

  const int  Mc = NB * 2048;
  const dim3 blk(256);
  const dim3 blk512(512);
  const dim3 gqkv(24, Mc / 256, 1);
  const dim3 gsc(16, 8, NB);
  const dim3 gpv(8, 8, NB);
  const dim3 go(8, Mc / 256, 1);
  const dim3 gtr(16, Mc / 64, 1);

  if (fullW) {
    for (int p = 0; p < 3; ++p)
      pack_w_kernel<<<1024, blk, 0, stream>>>(w_a[p], w_b[p],
          Wqkv + (size_t)(2*p)   * 2097152ull,
          Wqkv + (size_t)(2*p+1) * 2097152ull, neg_c2);
    pack_w_kernel<<<1024, blk, 0, stream>>>(w_a[3], w_b[3],
        Wo, Wo + 2097152ull, neg_c2);
  }

  for (int c = 0; c < 4 / NB; ++c) {
    const size_t xoff = (size_t)c * NB * 2097152ull;
    pack_x_kernel<<<Mc, blk, 0, stream>>>(xa + xoff, xb + xoff, R0, Mc * 256);

    if (!fullW)
      for (int p = 0; p < 3; ++p)
        pack_w_kernel<<<1024, blk, 0, stream>>>(w_a[p], w_b[p],
            Wqkv + (size_t)(2*p)   * 2097152ull,
            Wqkv + (size_t)(2*p+1) * 2097152ull, neg_c2);

    // fused QKV: [Mc,6144] = Xcat @ Wqkv^T, routed epilogue
    gemm256_kernel<0><<<gqkv, blk512, 0, stream>>>(R0, Wqkv, 2048, 2048, 2048, 0, 0,
        R1, Kc, R4, b_a[0], b_b[0], b_a[1], b_b[1], b_a[2], b_b[2], neg_c2);

    // V transpose into R5 = per-batch [Va^T ; Vb^T]
    transpose_v_kernel<<<gtr, blk, 0, stream>>>(R4, R5, 0,    0);
    transpose_v_kernel<<<gtr, blk, 0, stream>>>(R4, R5, 1024, 1024);

    // fused scores: [2048,4096] per batch = Qcat_b @ Kc_b^T -> sa(R0), sb(R4)
    gemm256_kernel<1><<<gsc, blk512, 0, stream>>>(R1, Kc, 2048, 2048, 2048, 4194304, 8388608,
        R0, R4, nullptr, nullptr, nullptr, nullptr, nullptr, nullptr, nullptr, 0.f);

    // magnitude + softmax -> bf16 attn (in-place over R0)
    softmax_mag_kernel<<<Mc, blk, 0, stream>>>(R0, R4, R0);

    // PV: [out_a|out_b] = attn @ Vt^T -> R1
    gemm256_kernel<2><<<gpv, blk512, 0, stream>>>(R0, R5, 2048, 2048, 2048, 4194304, 4194304,
        R1, nullptr, nullptr, nullptr, nullptr, nullptr, nullptr, nullptr, nullptr, 0.f);

    // fused O projection -> fp32 out_a / out_b
    if (!fullW)
      pack_w_kernel<<<1024, blk, 0, stream>>>(w_a[3], w_b[3], Wo, Wo + 2097152ull, neg_c2);
    gemm256_kernel<3><<<go, blk512, 0, stream>>>(R1, Wo, 2048, 2048, 2048, 0, 0,
        out + xoff, out + 8388608ull + xoff, nullptr,
        b_a[3], b_b[3], nullptr, nullptr, nullptr, nullptr, 0.f);
  }
}